// Round 3
// baseline (126.058 us; speedup 1.0000x reference)
//
#include <hip/hip_runtime.h>

#define IN_CH 64
#define OUT_CH 128
#define HW 128
#define KTAPS 9
#define KDIM (IN_CH * KTAPS)   // 576
#define ROWB 16384             // bytes per (n,h) row image: 128 w * 64 ic * 2B

typedef __bf16 bf16x8 __attribute__((ext_vector_type(8)));
typedef float f32x16 __attribute__((ext_vector_type(16)));
typedef float f32x4 __attribute__((ext_vector_type(4)));

// fp32 -> bf16 round-to-nearest-even (data has no NaN/Inf)
__device__ __forceinline__ unsigned f2bf(float f) {
    unsigned u = __builtin_bit_cast(unsigned, f);
    return (u + 0x7FFFu + ((u >> 16) & 1u)) >> 16;
}

// 16B-granule XOR swizzle keyed by w (3 bits -> byte-addr bits 4..6).
// Baked into xb's global layout by xprep; conv reads with the same key.
__device__ __forceinline__ int swz(int w) { return ((w ^ (w >> 3)) & 7) << 4; }

__device__ __forceinline__ void gload_lds16(const void* g, void* l) {
    __builtin_amdgcn_global_load_lds(
        (const __attribute__((address_space(1))) unsigned int*)g,
        (__attribute__((address_space(3))) unsigned int*)l, 16, 0, 0);
}

// W (OIHW fp32, 128x64x3x3) -> Wl bf16 [oc][tap][ic], tap = kh*3+kw
__global__ void wprep_kernel(const float* __restrict__ W, unsigned short* __restrict__ Wl) {
    int i = blockIdx.x * blockDim.x + threadIdx.x;
    if (i >= OUT_CH * IN_CH * KTAPS) return;
    int oc  = i / (IN_CH * KTAPS);
    int r   = i % (IN_CH * KTAPS);
    int tap = r >> 6;
    int ic  = r & 63;
    int kh = tap / 3, kw = tap % 3;
    Wl[i] = (unsigned short)f2bf(W[((oc * IN_CH + ic) * 3 + kh) * 3 + kw]);
}

// x (NCHW fp32) -> xb[n][h] = 16KB bf16 image [w][ic], swizzle pre-baked.
__global__ __launch_bounds__(256) void xprep_kernel(const float* __restrict__ x,
                                                    unsigned short* __restrict__ xb) {
    __shared__ __align__(16) unsigned char img[ROWB];
    int bid = blockIdx.x;
    int n = bid >> 7, h = bid & 127;
    int tid = threadIdx.x;
    int w4 = tid & 31, ic8 = tid >> 5;
    const float* xp = x + (((n * IN_CH + ic8 * 8) * HW + h) * HW + w4 * 4);
    f32x4 v[8];
    #pragma unroll
    for (int j = 0; j < 8; ++j) v[j] = *reinterpret_cast<const f32x4*>(xp + j * (HW * HW));
    #pragma unroll
    for (int j2 = 0; j2 < 4; ++j2) {
        int w = w4 * 4 + j2;
        uint4 pk;
        pk.x = f2bf(v[0][j2]) | (f2bf(v[1][j2]) << 16);
        pk.y = f2bf(v[2][j2]) | (f2bf(v[3][j2]) << 16);
        pk.z = f2bf(v[4][j2]) | (f2bf(v[5][j2]) << 16);
        pk.w = f2bf(v[6][j2]) | (f2bf(v[7][j2]) << 16);
        *reinterpret_cast<uint4*>(img + ((w * 128 + ic8 * 16) ^ swz(w))) = pk;
    }
    __syncthreads();
    // linear dump: LDS image -> xb row (both conflict-free / coalesced)
    const uint4* s = reinterpret_cast<const uint4*>(img);
    uint4* d = reinterpret_cast<uint4*>(xb) + (size_t)bid * 1024;
    #pragma unroll
    for (int r = 0; r < 4; ++r) d[r * 256 + tid] = s[r * 256 + tid];
}

// Fast conv: stage 3 pre-converted rows via global_load_lds, then MFMA GEMM.
__global__ __launch_bounds__(256, 3) void conv_kernel_f(
    const unsigned short* __restrict__ xb, const unsigned short* __restrict__ Wl,
    const float* __restrict__ bias, float* __restrict__ y)
{
    __shared__ __align__(16) unsigned char xs[3 * ROWB];  // 48 KiB -> 3 blocks/CU

    int bid = blockIdx.x;
    int sb  = (bid & 7) * 256 + (bid >> 3);   // XCD-contiguous h ranges (bijective: 2048 = 8*256)
    int n = sb >> 7, h = sb & 127;
    int tid = threadIdx.x;
    int wid = tid >> 6, lane = tid & 63;

    // ---- stage: 12 x global_load_lds_dwordx4 per thread, zero VALU conversion ----
    #pragma unroll
    for (int kh = 0; kh < 3; ++kh) {
        int srow = (h + kh * 8 + 120) & 127;   // h-8, h, h+8 (mod 128)
        const unsigned char* src = (const unsigned char*)xb + (size_t)(n * HW + srow) * ROWB;
        #pragma unroll
        for (int j = 0; j < 4; ++j) {
            int off = wid * 4096 + j * 1024;   // wave-uniform LDS base
            gload_lds16(src + off + lane * 16, xs + kh * ROWB + off);
        }
    }
    __syncthreads();

    // ---- implicit GEMM: Y[128 oc][128 w] = Wl[128][576] * X[576][128] ----
    int wr = wid >> 1, wc = wid & 1;
    int l31 = lane & 31, lhi = lane >> 5;

    f32x16 acc[2][2];
    #pragma unroll
    for (int a = 0; a < 2; ++a)
        #pragma unroll
        for (int bq = 0; bq < 2; ++bq)
            #pragma unroll
            for (int r = 0; r < 16; ++r) acc[a][bq][r] = 0.0f;

    const unsigned short* A0 = Wl + (wr * 64 + l31) * KDIM + lhi * 8;
    const unsigned short* A1 = A0 + 32 * KDIM;

    // Fully unrolled tap loop: compiler prefetches A-loads/B-reads across taps
    // under the launch_bounds(256,3) VGPR cap.
    #pragma unroll
    for (int kh = 0; kh < 3; ++kh) {
        #pragma unroll
        for (int kw = 0; kw < 3; ++kw) {
            int tap = kh * 3 + kw;
            int xc0 = (wc * 64 + l31 + 8 * kw - 8) & 127;   // circular column
            int xc1 = (xc0 + 32) & 127;
            int b0base = kh * ROWB + xc0 * 128 + lhi * 16, s0 = swz(xc0);
            int b1base = kh * ROWB + xc1 * 128 + lhi * 16, s1 = swz(xc1);
            const unsigned short* At = A0 + tap * 64;
            const unsigned short* Au = A1 + tap * 64;
            #pragma unroll
            for (int ks = 0; ks < 4; ++ks) {   // K=16 per MFMA, 64 ic per tap
                bf16x8 a0 = *reinterpret_cast<const bf16x8*>(At + ks * 16);
                bf16x8 a1 = *reinterpret_cast<const bf16x8*>(Au + ks * 16);
                bf16x8 b0 = *reinterpret_cast<const bf16x8*>(xs + ((b0base + ks * 32) ^ s0));
                bf16x8 b1 = *reinterpret_cast<const bf16x8*>(xs + ((b1base + ks * 32) ^ s1));
                acc[0][0] = __builtin_amdgcn_mfma_f32_32x32x16_bf16(a0, b0, acc[0][0], 0, 0, 0);
                acc[0][1] = __builtin_amdgcn_mfma_f32_32x32x16_bf16(a0, b1, acc[0][1], 0, 0, 0);
                acc[1][0] = __builtin_amdgcn_mfma_f32_32x32x16_bf16(a1, b0, acc[1][0], 0, 0, 0);
                acc[1][1] = __builtin_amdgcn_mfma_f32_32x32x16_bf16(a1, b1, acc[1][1], 0, 0, 0);
            }
        }
    }

    // ---- epilogue: bias + store. D: col=l31(w), row=(reg&3)+8*(reg>>2)+4*lhi ----
    int outbase = (n * OUT_CH) * HW * HW + h * HW;
    #pragma unroll
    for (int mi = 0; mi < 2; ++mi) {
        #pragma unroll
        for (int ni = 0; ni < 2; ++ni) {
            int wcol = wc * 64 + ni * 32 + l31;
            #pragma unroll
            for (int reg = 0; reg < 16; ++reg) {
                int oc = wr * 64 + mi * 32 + (reg & 3) + 8 * (reg >> 2) + 4 * lhi;
                y[outbase + oc * HW * HW + wcol] = acc[mi][ni][reg] + bias[oc];
            }
        }
    }
}

// Fallback (proven R2 path) if d_ws can't hold xb.
__global__ __launch_bounds__(256, 3) void conv_kernel_s(
    const float* __restrict__ x, const unsigned short* __restrict__ Wl,
    const float* __restrict__ bias, float* __restrict__ y)
{
    __shared__ __align__(16) unsigned char xs[3 * ROWB];
    int bid = blockIdx.x;
    int sb  = (bid & 7) * 256 + (bid >> 3);
    int n = sb >> 7, h = sb & 127;
    int tid = threadIdx.x;

    #pragma unroll
    for (int it = 0; it < 3; ++it) {
        int q   = it * 256 + tid;
        int w4  = q & 31;
        int ic8 = (q >> 5) & 7;
        int kh  = q >> 8;
        int srow = (h + kh * 8 + 120) & 127;
        const float* xp = x + (((n * IN_CH + ic8 * 8) * HW + srow) * HW + w4 * 4);
        f32x4 v[8];
        #pragma unroll
        for (int j = 0; j < 8; ++j)
            v[j] = *reinterpret_cast<const f32x4*>(xp + j * (HW * HW));
        #pragma unroll
        for (int j2 = 0; j2 < 4; ++j2) {
            int w = w4 * 4 + j2;
            uint4 pk;
            pk.x = f2bf(v[0][j2]) | (f2bf(v[1][j2]) << 16);
            pk.y = f2bf(v[2][j2]) | (f2bf(v[3][j2]) << 16);
            pk.z = f2bf(v[4][j2]) | (f2bf(v[5][j2]) << 16);
            pk.w = f2bf(v[6][j2]) | (f2bf(v[7][j2]) << 16);
            *reinterpret_cast<uint4*>(xs + kh * ROWB + ((w * 128 + ic8 * 16) ^ swz(w))) = pk;
        }
    }
    __syncthreads();

    int wid  = tid >> 6;
    int lane = tid & 63;
    int wr = wid >> 1, wc = wid & 1;
    int l31 = lane & 31, lhi = lane >> 5;

    f32x16 acc[2][2];
    #pragma unroll
    for (int a = 0; a < 2; ++a)
        #pragma unroll
        for (int bq = 0; bq < 2; ++bq)
            #pragma unroll
            for (int r = 0; r < 16; ++r) acc[a][bq][r] = 0.0f;

    const unsigned short* A0 = Wl + (wr * 64 + l31) * KDIM + lhi * 8;
    const unsigned short* A1 = A0 + 32 * KDIM;

    #pragma unroll 1
    for (int kh = 0; kh < 3; ++kh) {
        #pragma unroll
        for (int kw = 0; kw < 3; ++kw) {
            int tap = kh * 3 + kw;
            int xc0 = (wc * 64 + l31 + 8 * kw - 8) & 127;
            int xc1 = (xc0 + 32) & 127;
            int b0base = kh * ROWB + xc0 * 128 + lhi * 16, s0 = swz(xc0);
            int b1base = kh * ROWB + xc1 * 128 + lhi * 16, s1 = swz(xc1);
            const unsigned short* At = A0 + tap * 64;
            const unsigned short* Au = A1 + tap * 64;
            #pragma unroll
            for (int ks = 0; ks < 4; ++ks) {
                bf16x8 a0 = *reinterpret_cast<const bf16x8*>(At + ks * 16);
                bf16x8 a1 = *reinterpret_cast<const bf16x8*>(Au + ks * 16);
                bf16x8 b0 = *reinterpret_cast<const bf16x8*>(xs + ((b0base + ks * 32) ^ s0));
                bf16x8 b1 = *reinterpret_cast<const bf16x8*>(xs + ((b1base + ks * 32) ^ s1));
                acc[0][0] = __builtin_amdgcn_mfma_f32_32x32x16_bf16(a0, b0, acc[0][0], 0, 0, 0);
                acc[0][1] = __builtin_amdgcn_mfma_f32_32x32x16_bf16(a0, b1, acc[0][1], 0, 0, 0);
                acc[1][0] = __builtin_amdgcn_mfma_f32_32x32x16_bf16(a1, b0, acc[1][0], 0, 0, 0);
                acc[1][1] = __builtin_amdgcn_mfma_f32_32x32x16_bf16(a1, b1, acc[1][1], 0, 0, 0);
            }
        }
    }

    int outbase = (n * OUT_CH) * HW * HW + h * HW;
    #pragma unroll
    for (int mi = 0; mi < 2; ++mi) {
        #pragma unroll
        for (int ni = 0; ni < 2; ++ni) {
            int wcol = wc * 64 + ni * 32 + l31;
            #pragma unroll
            for (int reg = 0; reg < 16; ++reg) {
                int oc = wr * 64 + mi * 32 + (reg & 3) + 8 * (reg >> 2) + 4 * lhi;
                y[outbase + oc * HW * HW + wcol] = acc[mi][ni][reg] + bias[oc];
            }
        }
    }
}

extern "C" void kernel_launch(void* const* d_in, const int* in_sizes, int n_in,
                              void* d_out, int out_size, void* d_ws, size_t ws_size,
                              hipStream_t stream) {
    const float* x = (const float*)d_in[0];
    const float* W = (const float*)d_in[1];
    const float* b = (const float*)d_in[2];
    float* y = (float*)d_out;

    unsigned short* Wl = (unsigned short*)d_ws;                               // 147456 B at offset 0
    unsigned short* xb = (unsigned short*)((char*)d_ws + 262144);             // 32 MiB, 16KB-aligned
    const size_t need = 262144 + (size_t)16 * HW * ROWB;                      // ~33.8 MB

    hipLaunchKernelGGL(wprep_kernel, dim3((OUT_CH * IN_CH * KTAPS + 255) / 256), dim3(256), 0, stream, W, Wl);
    if (ws_size >= need) {
        hipLaunchKernelGGL(xprep_kernel, dim3(16 * HW), dim3(256), 0, stream, x, xb);
        hipLaunchKernelGGL(conv_kernel_f, dim3(16 * HW), dim3(256), 0, stream, xb, Wl, b, y);
    } else {
        hipLaunchKernelGGL(conv_kernel_s, dim3(16 * HW), dim3(256), 0, stream, x, Wl, b, y);
    }
}

// Round 4
// 79.775 us; speedup vs baseline: 1.5802x; 1.5802x over previous
//
#include <hip/hip_runtime.h>

#define IN_CH 64
#define OUT_CH 128
#define HW 128
#define KTAPS 9
#define KDIM (IN_CH * KTAPS)   // 576
#define ROWB 16384             // bytes per (n,h) row image: 128 w * 64 ic * 2B
#define ATILE 16384            // bytes per tap A-tile: 128 oc * 64 ic * 2B

typedef __bf16 bf16x8 __attribute__((ext_vector_type(8)));
typedef float f32x16 __attribute__((ext_vector_type(16)));
typedef float f32x4 __attribute__((ext_vector_type(4)));

// fp32 -> bf16 round-to-nearest-even (data has no NaN/Inf)
__device__ __forceinline__ unsigned f2bf(float f) {
    unsigned u = __builtin_bit_cast(unsigned, f);
    return (u + 0x7FFFu + ((u >> 16) & 1u)) >> 16;
}

// 16B-granule XOR swizzle keyed by row (3 bits -> byte-addr bits 4..6).
// Baked into the GLOBAL layout of both xb (by xprep) and Wl (by wprep), so
// global_load_lds can stage linearly; reads apply the same key. Spreads a
// wave's 32 stride-128B row accesses over 8 banks-groups (conflict-free b128).
__device__ __forceinline__ int swz(int r) { return ((r ^ (r >> 3)) & 7) << 4; }

__device__ __forceinline__ void gload_lds16(const void* g, void* l) {
    __builtin_amdgcn_global_load_lds(
        (const __attribute__((address_space(1))) unsigned int*)g,
        (__attribute__((address_space(3))) unsigned int*)l, 16, 0, 0);
}

// W (OIHW fp32, 128x64x3x3) -> Wl: 9 tap-tiles of 16KB, tile[tap] holds
// bf16 A[oc][ic] at byte (oc*128 + ic*2) ^ swz(oc). tap = kh*3+kw.
__global__ void wprep_kernel(const float* __restrict__ W, unsigned short* __restrict__ Wl) {
    int i = blockIdx.x * blockDim.x + threadIdx.x;
    if (i >= OUT_CH * IN_CH * KTAPS) return;
    int tap = i >> 13;          // i = tap*8192 + oc*64 + ic
    int oc  = (i >> 6) & 127;
    int ic  = i & 63;
    int kh = tap / 3, kw = tap % 3;
    float v = W[((oc * IN_CH + ic) * 3 + kh) * 3 + kw];
    int addr = (oc * 128 + ic * 2) ^ swz(oc);
    *(unsigned short*)((unsigned char*)Wl + tap * ATILE + addr) = (unsigned short)f2bf(v);
}

// x (NCHW fp32) -> xb[n][h] = 16KB bf16 image [w][ic], swizzle pre-baked.
__global__ __launch_bounds__(256) void xprep_kernel(const float* __restrict__ x,
                                                    unsigned short* __restrict__ xb) {
    __shared__ __align__(16) unsigned char img[ROWB];
    int bid = blockIdx.x;
    int n = bid >> 7, h = bid & 127;
    int tid = threadIdx.x;
    int w4 = tid & 31, ic8 = tid >> 5;
    const float* xp = x + (((n * IN_CH + ic8 * 8) * HW + h) * HW + w4 * 4);
    f32x4 v[8];
    #pragma unroll
    for (int j = 0; j < 8; ++j) v[j] = *reinterpret_cast<const f32x4*>(xp + j * (HW * HW));
    #pragma unroll
    for (int j2 = 0; j2 < 4; ++j2) {
        int w = w4 * 4 + j2;
        uint4 pk;
        pk.x = f2bf(v[0][j2]) | (f2bf(v[1][j2]) << 16);
        pk.y = f2bf(v[2][j2]) | (f2bf(v[3][j2]) << 16);
        pk.z = f2bf(v[4][j2]) | (f2bf(v[5][j2]) << 16);
        pk.w = f2bf(v[6][j2]) | (f2bf(v[7][j2]) << 16);
        *reinterpret_cast<uint4*>(img + ((w * 128 + ic8 * 16) ^ swz(w))) = pk;
    }
    __syncthreads();
    const uint4* s = reinterpret_cast<const uint4*>(img);
    uint4* d = reinterpret_cast<uint4*>(xb) + (size_t)bid * 1024;
    #pragma unroll
    for (int r = 0; r < 4; ++r) d[r * 256 + tid] = s[r * 256 + tid];
}

// conv: B (3 rows) staged once + A tap-tiles double-buffered through LDS.
// Inner loop is pure ds_read + MFMA; next tap's A-tile DMA flies under the
// current tap's MFMAs (2-phase T3-minimum schedule, one barrier per tap).
__global__ __launch_bounds__(256, 2) void conv_kernel_f(
    const unsigned short* __restrict__ xb, const unsigned short* __restrict__ Wl,
    const float* __restrict__ bias, float* __restrict__ y)
{
    __shared__ __align__(16) unsigned char xsB[3 * ROWB];   // 48 KiB
    __shared__ __align__(16) unsigned char xsA[2 * ATILE];  // 32 KiB  (total 80K -> 2 blocks/CU)

    int bid = blockIdx.x;
    int sb  = (bid & 7) * 256 + (bid >> 3);   // XCD-contiguous h ranges (bijective: 2048 = 8*256)
    int n = sb >> 7, h = sb & 127;
    int tid = threadIdx.x;
    int wid = tid >> 6, lane = tid & 63;

    // ---- prologue: stage 3 B-rows (12 loads) + A tap-0 (4 loads) ----
    #pragma unroll
    for (int kh = 0; kh < 3; ++kh) {
        int srow = (h + kh * 8 + 120) & 127;   // h-8, h, h+8 (mod 128)
        const unsigned char* src = (const unsigned char*)xb + (size_t)(n * HW + srow) * ROWB;
        #pragma unroll
        for (int j = 0; j < 4; ++j) {
            int off = wid * 4096 + j * 1024;   // wave-uniform LDS base
            gload_lds16(src + off + lane * 16, xsB + kh * ROWB + off);
        }
    }
    {
        const unsigned char* asrc = (const unsigned char*)Wl;   // tap 0 tile
        #pragma unroll
        for (int j = 0; j < 4; ++j) {
            int off = wid * 4096 + j * 1024;
            gload_lds16(asrc + off + lane * 16, xsA + off);
        }
    }
    __syncthreads();

    // ---- implicit GEMM: Y[128 oc][128 w] = A[128][576] * X[576][128] ----
    int wr = wid >> 1, wc = wid & 1;
    int l31 = lane & 31, lhi = lane >> 5;

    f32x16 acc[2][2];
    #pragma unroll
    for (int a = 0; a < 2; ++a)
        #pragma unroll
        for (int bq = 0; bq < 2; ++bq)
            #pragma unroll
            for (int r = 0; r < 16; ++r) acc[a][bq][r] = 0.0f;

    int arow0 = wr * 64 + l31, arow1 = arow0 + 32;
    int aoff0 = arow0 * 128 + lhi * 16, sa0 = swz(arow0);
    int aoff1 = arow1 * 128 + lhi * 16, sa1 = swz(arow1);

    #pragma unroll
    for (int t = 0; t < 9; ++t) {
        // phase 1: issue next tap's A-tile DMA (flies under this tap's MFMAs)
        if (t < 8) {
            const unsigned char* asrc = (const unsigned char*)Wl + (t + 1) * ATILE;
            unsigned char* adst = xsA + ((t + 1) & 1) * ATILE;
            #pragma unroll
            for (int j = 0; j < 4; ++j) {
                int off = wid * 4096 + j * 1024;
                gload_lds16(asrc + off + lane * 16, adst + off);
            }
        }
        // phase 2: ds_read + MFMA on current buffers
        const unsigned char* At = xsA + (t & 1) * ATILE;
        int kh = t / 3, kw = t % 3;
        int xc0 = (wc * 64 + l31 + 8 * kw - 8) & 127;   // circular column
        int xc1 = (xc0 + 32) & 127;
        int b0base = kh * ROWB + xc0 * 128 + lhi * 16, s0 = swz(xc0);
        int b1base = kh * ROWB + xc1 * 128 + lhi * 16, s1 = swz(xc1);
        #pragma unroll
        for (int ks = 0; ks < 4; ++ks) {   // K=16 per MFMA, 64 ic per tap
            bf16x8 a0 = *reinterpret_cast<const bf16x8*>(At + ((aoff0 + ks * 32) ^ sa0));
            bf16x8 a1 = *reinterpret_cast<const bf16x8*>(At + ((aoff1 + ks * 32) ^ sa1));
            bf16x8 b0 = *reinterpret_cast<const bf16x8*>(xsB + ((b0base + ks * 32) ^ s0));
            bf16x8 b1 = *reinterpret_cast<const bf16x8*>(xsB + ((b1base + ks * 32) ^ s1));
            acc[0][0] = __builtin_amdgcn_mfma_f32_32x32x16_bf16(a0, b0, acc[0][0], 0, 0, 0);
            acc[0][1] = __builtin_amdgcn_mfma_f32_32x32x16_bf16(a0, b1, acc[0][1], 0, 0, 0);
            acc[1][0] = __builtin_amdgcn_mfma_f32_32x32x16_bf16(a1, b0, acc[1][0], 0, 0, 0);
            acc[1][1] = __builtin_amdgcn_mfma_f32_32x32x16_bf16(a1, b1, acc[1][1], 0, 0, 0);
        }
        // barrier: all waves done reading buf[t&1] before it's overwritten at t+2;
        // compiler's drain also completes the just-issued t+1 loads (well-hidden).
        if (t < 8) __syncthreads();
    }

    // ---- epilogue: bias + store. D: col=l31(w), row=(reg&3)+8*(reg>>2)+4*lhi ----
    int outbase = (n * OUT_CH) * HW * HW + h * HW;
    #pragma unroll
    for (int mi = 0; mi < 2; ++mi) {
        #pragma unroll
        for (int ni = 0; ni < 2; ++ni) {
            int wcol = wc * 64 + ni * 32 + l31;
            #pragma unroll
            for (int reg = 0; reg < 16; ++reg) {
                int oc = wr * 64 + mi * 32 + (reg & 3) + 8 * (reg >> 2) + 4 * lhi;
                y[outbase + oc * HW * HW + wcol] = acc[mi][ni][reg] + bias[oc];
            }
        }
    }
}

extern "C" void kernel_launch(void* const* d_in, const int* in_sizes, int n_in,
                              void* d_out, int out_size, void* d_ws, size_t ws_size,
                              hipStream_t stream) {
    const float* x = (const float*)d_in[0];
    const float* W = (const float*)d_in[1];
    const float* b = (const float*)d_in[2];
    float* y = (float*)d_out;

    unsigned short* Wl = (unsigned short*)d_ws;                    // 147456 B at offset 0
    unsigned short* xb = (unsigned short*)((char*)d_ws + 262144);  // 32 MiB, 16KB-aligned
    // ws sufficiency (34 MB) proven in R3 (fast path ran & validated).

    hipLaunchKernelGGL(wprep_kernel, dim3((OUT_CH * IN_CH * KTAPS + 255) / 256), dim3(256), 0, stream, W, Wl);
    hipLaunchKernelGGL(xprep_kernel, dim3(16 * HW), dim3(256), 0, stream, x, xb);
    hipLaunchKernelGGL(conv_kernel_f, dim3(16 * HW), dim3(256), 0, stream, xb, Wl, b, y);
}

// Round 5
// 72.757 us; speedup vs baseline: 1.7326x; 1.0965x over previous
//
#include <hip/hip_runtime.h>

#define IN_CH 64
#define OUT_CH 128
#define HW 128
#define KTAPS 9
#define ROWB 16384             // bytes per staged row image: 128 w * 64 ic * 2B
#define ATILE 16384            // bytes per tap A-tile: 128 oc * 64 ic * 2B

typedef __bf16 bf16x8 __attribute__((ext_vector_type(8)));
typedef float f32x16 __attribute__((ext_vector_type(16)));
typedef float f32x4 __attribute__((ext_vector_type(4)));

// fp32 -> bf16 round-to-nearest-even (data has no NaN/Inf)
__device__ __forceinline__ unsigned f2bf(float f) {
    unsigned u = __builtin_bit_cast(unsigned, f);
    return (u + 0x7FFFu + ((u >> 16) & 1u)) >> 16;
}

// 16B-granule XOR swizzle keyed by row (3 bits -> byte-addr bits 4..6).
// Baked into Wl's GLOBAL layout (so global_load_lds stages linearly) and
// applied on LDS writes/reads for B. Spreads a wave's 32 stride-128B row
// accesses over 8 bank-groups -> conflict-free ds_read_b128.
__device__ __forceinline__ int swz(int r) { return ((r ^ (r >> 3)) & 7) << 4; }

__device__ __forceinline__ void gload_lds16(const void* g, void* l) {
    __builtin_amdgcn_global_load_lds(
        (const __attribute__((address_space(1))) unsigned int*)g,
        (__attribute__((address_space(3))) unsigned int*)l, 16, 0, 0);
}

// W (OIHW fp32, 128x64x3x3) -> Wl: 9 tap-tiles of 16KB, tile[tap] holds
// bf16 A[oc][ic] at byte (oc*128 + ic*2) ^ swz(oc). tap = kh*3+kw.
__global__ void wprep_kernel(const float* __restrict__ W, unsigned short* __restrict__ Wl) {
    int i = blockIdx.x * blockDim.x + threadIdx.x;
    if (i >= OUT_CH * IN_CH * KTAPS) return;
    int tap = i >> 13;          // i = tap*8192 + oc*64 + ic
    int oc  = (i >> 6) & 127;
    int ic  = i & 63;
    int kh = tap / 3, kw = tap % 3;
    float v = W[((oc * IN_CH + ic) * 3 + kh) * 3 + kw];
    int addr = (oc * 128 + ic * 2) ^ swz(oc);
    *(unsigned short*)((unsigned char*)Wl + tap * ATILE + addr) = (unsigned short)f2bf(v);
}

// Fused conv: B staged from fp32 x in the prologue (convert+swizzle in reg),
// A tap-tiles double-buffered through LDS via global_load_lds; inner loop is
// pure ds_read + MFMA (2-phase schedule, one barrier per tap). Block B's
// prologue hides under block A's main loop (2 blocks/CU).
__global__ __launch_bounds__(256, 2) void conv_kernel_f(
    const float* __restrict__ x, const unsigned short* __restrict__ Wl,
    const float* __restrict__ bias, float* __restrict__ y)
{
    __shared__ __align__(16) unsigned char xsB[3 * ROWB];   // 48 KiB
    __shared__ __align__(16) unsigned char xsA[2 * ATILE];  // 32 KiB  (80K -> 2 blocks/CU)

    int bid = blockIdx.x;
    int sb  = (bid & 7) * 256 + (bid >> 3);   // XCD-contiguous h ranges (bijective: 2048 = 8*256)
    int n = sb >> 7, h = sb & 127;
    int tid = threadIdx.x;
    int wid = tid >> 6, lane = tid & 63;

    // ---- prologue ----
    // 1) tap-0 A-tile DMA first: flies under the whole B-staging phase.
    {
        const unsigned char* asrc = (const unsigned char*)Wl;
        #pragma unroll
        for (int j = 0; j < 4; ++j) {
            int off = wid * 4096 + j * 1024;   // wave-uniform LDS base
            gload_lds16(asrc + off + lane * 16, xsA + off);
        }
    }
    // 2) stage 3 B-rows (h-8, h, h+8) from fp32 x: convert + swizzled write.
    //    768 groups: (kh, ic8, w4); per group 8 coalesced float4 loads,
    //    pack 8 ic -> uint4, 4 swizzled ds_write_b128.
    #pragma unroll
    for (int it = 0; it < 3; ++it) {
        int q   = it * 256 + tid;    // 0..767
        int w4  = q & 31;
        int ic8 = (q >> 5) & 7;
        int kh  = q >> 8;
        int srow = (h + kh * 8 + 120) & 127;   // h-8, h, h+8 (mod 128)
        const float* xp = x + (((n * IN_CH + ic8 * 8) * HW + srow) * HW + w4 * 4);
        f32x4 v[8];
        #pragma unroll
        for (int j = 0; j < 8; ++j)
            v[j] = *reinterpret_cast<const f32x4*>(xp + j * (HW * HW));
        #pragma unroll
        for (int j2 = 0; j2 < 4; ++j2) {
            int w = w4 * 4 + j2;
            uint4 pk;
            pk.x = f2bf(v[0][j2]) | (f2bf(v[1][j2]) << 16);
            pk.y = f2bf(v[2][j2]) | (f2bf(v[3][j2]) << 16);
            pk.z = f2bf(v[4][j2]) | (f2bf(v[5][j2]) << 16);
            pk.w = f2bf(v[6][j2]) | (f2bf(v[7][j2]) << 16);
            *reinterpret_cast<uint4*>(xsB + kh * ROWB + ((w * 128 + ic8 * 16) ^ swz(w))) = pk;
        }
    }
    __syncthreads();

    // ---- implicit GEMM: Y[128 oc][128 w] = A[128][576] * X[576][128] ----
    int wr = wid >> 1, wc = wid & 1;
    int l31 = lane & 31, lhi = lane >> 5;

    f32x16 acc[2][2];
    #pragma unroll
    for (int a = 0; a < 2; ++a)
        #pragma unroll
        for (int bq = 0; bq < 2; ++bq)
            #pragma unroll
            for (int r = 0; r < 16; ++r) acc[a][bq][r] = 0.0f;

    int arow0 = wr * 64 + l31, arow1 = arow0 + 32;
    int aoff0 = arow0 * 128 + lhi * 16, sa0 = swz(arow0);
    int aoff1 = arow1 * 128 + lhi * 16, sa1 = swz(arow1);

    #pragma unroll
    for (int t = 0; t < 9; ++t) {
        // phase 1: issue next tap's A-tile DMA (flies under this tap's MFMAs)
        if (t < 8) {
            const unsigned char* asrc = (const unsigned char*)Wl + (t + 1) * ATILE;
            unsigned char* adst = xsA + ((t + 1) & 1) * ATILE;
            #pragma unroll
            for (int j = 0; j < 4; ++j) {
                int off = wid * 4096 + j * 1024;
                gload_lds16(asrc + off + lane * 16, adst + off);
            }
        }
        // phase 2: ds_read + MFMA on current buffers
        const unsigned char* At = xsA + (t & 1) * ATILE;
        int kh = t / 3, kw = t % 3;
        int xc0 = (wc * 64 + l31 + 8 * kw - 8) & 127;   // circular column
        int xc1 = (xc0 + 32) & 127;
        int b0base = kh * ROWB + xc0 * 128 + lhi * 16, s0 = swz(xc0);
        int b1base = kh * ROWB + xc1 * 128 + lhi * 16, s1 = swz(xc1);
        #pragma unroll
        for (int ks = 0; ks < 4; ++ks) {   // K=16 per MFMA, 64 ic per tap
            bf16x8 a0 = *reinterpret_cast<const bf16x8*>(At + ((aoff0 + ks * 32) ^ sa0));
            bf16x8 a1 = *reinterpret_cast<const bf16x8*>(At + ((aoff1 + ks * 32) ^ sa1));
            bf16x8 b0 = *reinterpret_cast<const bf16x8*>(xsB + ((b0base + ks * 32) ^ s0));
            bf16x8 b1 = *reinterpret_cast<const bf16x8*>(xsB + ((b1base + ks * 32) ^ s1));
            acc[0][0] = __builtin_amdgcn_mfma_f32_32x32x16_bf16(a0, b0, acc[0][0], 0, 0, 0);
            acc[0][1] = __builtin_amdgcn_mfma_f32_32x32x16_bf16(a0, b1, acc[0][1], 0, 0, 0);
            acc[1][0] = __builtin_amdgcn_mfma_f32_32x32x16_bf16(a1, b0, acc[1][0], 0, 0, 0);
            acc[1][1] = __builtin_amdgcn_mfma_f32_32x32x16_bf16(a1, b1, acc[1][1], 0, 0, 0);
        }
        // barrier: all waves done reading A-buf[t&1] before it's overwritten at t+2;
        // also drains the just-issued t+1 DMA (hidden under the 16-MFMA phase).
        if (t < 8) __syncthreads();
    }

    // ---- epilogue: bias + store. D: col=l31(w), row=(reg&3)+8*(reg>>2)+4*lhi ----
    int outbase = (n * OUT_CH) * HW * HW + h * HW;
    #pragma unroll
    for (int mi = 0; mi < 2; ++mi) {
        #pragma unroll
        for (int ni = 0; ni < 2; ++ni) {
            int wcol = wc * 64 + ni * 32 + l31;
            #pragma unroll
            for (int reg = 0; reg < 16; ++reg) {
                int oc = wr * 64 + mi * 32 + (reg & 3) + 8 * (reg >> 2) + 4 * lhi;
                y[outbase + oc * HW * HW + wcol] = acc[mi][ni][reg] + bias[oc];
            }
        }
    }
}

extern "C" void kernel_launch(void* const* d_in, const int* in_sizes, int n_in,
                              void* d_out, int out_size, void* d_ws, size_t ws_size,
                              hipStream_t stream) {
    const float* x = (const float*)d_in[0];
    const float* W = (const float*)d_in[1];
    const float* b = (const float*)d_in[2];
    float* y = (float*)d_out;

    unsigned short* Wl = (unsigned short*)d_ws;   // 147456 B

    hipLaunchKernelGGL(wprep_kernel, dim3((OUT_CH * IN_CH * KTAPS + 255) / 256), dim3(256), 0, stream, W, Wl);
    hipLaunchKernelGGL(conv_kernel_f, dim3(16 * HW), dim3(256), 0, stream, x, Wl, b, y);
}

// Round 6
// 68.246 us; speedup vs baseline: 1.8471x; 1.0661x over previous
//
#include <hip/hip_runtime.h>

#define IN_CH 64
#define OUT_CH 128
#define HW 128
#define KTAPS 9
#define ROWB 16384             // bytes per staged row image: 128 w * 64 ic * 2B

typedef __bf16 bf16x8 __attribute__((ext_vector_type(8)));
typedef float f32x16 __attribute__((ext_vector_type(16)));
typedef float f32x4 __attribute__((ext_vector_type(4)));

// fp32 -> bf16 round-to-nearest-even (data has no NaN/Inf)
__device__ __forceinline__ unsigned f2bf(float f) {
    unsigned u = __builtin_bit_cast(unsigned, f);
    return (u + 0x7FFFu + ((u >> 16) & 1u)) >> 16;
}

// 16B-granule XOR swizzle keyed by row (3 bits -> byte-addr bits 4..6).
// Applied on B's LDS writes/reads: spreads a wave's 32 stride-128B row
// accesses over 8 bank-groups -> conflict-free ds_read_b128.
__device__ __forceinline__ int swz(int r) { return ((r ^ (r >> 3)) & 7) << 4; }

// W (OIHW fp32) -> Wl in wave-fragment order:
// 16B chunk index = (p*9 + t)*512 + (m*4 + ks)*64 + lane
//   p = oc-half (wave wr), t = tap, m = 32-row group, ks = K16 slice, lane = MFMA lane.
// Chunk content: 8 bf16 of A[oc = p*64+m*32+(lane&31)][ic = ks*16+(lane>>5)*8 .. +8].
// A wave's per-tap A-fragment loads become 8 lane-contiguous 1KB dwordx4 loads.
__global__ void wprep_kernel(const float* __restrict__ W, unsigned short* __restrict__ Wl) {
    int i = blockIdx.x * blockDim.x + threadIdx.x;   // 73728 bf16 elements
    if (i >= OUT_CH * IN_CH * KTAPS) return;
    int p  = i / 36864;
    int r  = i % 36864;
    int t  = r >> 12;          // 0..8
    int r2 = r & 4095;
    int m  = r2 >> 11;
    int ks = (r2 >> 9) & 3;
    int l  = (r2 >> 3) & 63;
    int e  = r2 & 7;
    int oc = p * 64 + m * 32 + (l & 31);
    int ic = ks * 16 + (l >> 5) * 8 + e;
    int kh = t / 3, kw = t % 3;
    Wl[i] = (unsigned short)f2bf(W[((oc * IN_CH + ic) * 3 + kh) * 3 + kw]);
}

// Fused conv: B (3 x-rows) converted+staged to LDS once; A lives in registers,
// double-buffered per tap with one-tap-ahead prefetch from the L2-resident Wl.
// K-loop has ZERO barriers (B is read-only after the single staging barrier).
__global__ __launch_bounds__(256, 3) void conv_kernel_f(
    const float* __restrict__ x, const unsigned short* __restrict__ Wl,
    const float* __restrict__ bias, float* __restrict__ y)
{
    __shared__ __align__(16) unsigned char xsB[3 * ROWB];   // 48 KiB -> 3 blocks/CU

    int bid = blockIdx.x;
    int sb  = (bid & 7) * 256 + (bid >> 3);   // XCD-contiguous h ranges (bijective: 2048 = 8*256)
    int n = sb >> 7, h = sb & 127;
    int tid = threadIdx.x;
    int wid = tid >> 6, lane = tid & 63;
    int wr = wid >> 1, wc = wid & 1;
    int l31 = lane & 31, lhi = lane >> 5;

    // A chunk pointer (16B units): wave half wr, per-lane chunk.
    const bf16x8* Ab = reinterpret_cast<const bf16x8*>(Wl) + wr * (9 * 512) + lane;

    // Issue tap-0 A-frag loads first: in flight during the whole staging phase.
    bf16x8 aBuf[2][8];
    #pragma unroll
    for (int j = 0; j < 8; ++j) aBuf[0][j] = Ab[j * 64];

    // ---- stage 3 B-rows (h-8, h, h+8) from fp32 x: convert + swizzled write ----
    #pragma unroll
    for (int it = 0; it < 3; ++it) {
        int q   = it * 256 + tid;    // 0..767: (kh, ic8, w4)
        int w4  = q & 31;
        int ic8 = (q >> 5) & 7;
        int kh  = q >> 8;
        int srow = (h + kh * 8 + 120) & 127;   // h-8, h, h+8 (mod 128)
        const float* xp = x + (((n * IN_CH + ic8 * 8) * HW + srow) * HW + w4 * 4);
        f32x4 v[8];
        #pragma unroll
        for (int j = 0; j < 8; ++j)
            v[j] = *reinterpret_cast<const f32x4*>(xp + j * (HW * HW));
        #pragma unroll
        for (int j2 = 0; j2 < 4; ++j2) {
            int w = w4 * 4 + j2;
            uint4 pk;
            pk.x = f2bf(v[0][j2]) | (f2bf(v[1][j2]) << 16);
            pk.y = f2bf(v[2][j2]) | (f2bf(v[3][j2]) << 16);
            pk.z = f2bf(v[4][j2]) | (f2bf(v[5][j2]) << 16);
            pk.w = f2bf(v[6][j2]) | (f2bf(v[7][j2]) << 16);
            *reinterpret_cast<uint4*>(xsB + kh * ROWB + ((w * 128 + ic8 * 16) ^ swz(w))) = pk;
        }
    }
    __syncthreads();   // the ONLY barrier

    // ---- implicit GEMM: Y[128 oc][128 w] = A[128][576] * X[576][128] ----
    f32x16 acc[2][2];
    #pragma unroll
    for (int a = 0; a < 2; ++a)
        #pragma unroll
        for (int bq = 0; bq < 2; ++bq)
            #pragma unroll
            for (int r = 0; r < 16; ++r) acc[a][bq][r] = 0.0f;

    #pragma unroll
    for (int t = 0; t < 9; ++t) {
        // prefetch tap t+1's A-frags (consumed next iteration; loads fly under MFMAs)
        if (t < 8) {
            #pragma unroll
            for (int j = 0; j < 8; ++j)
                aBuf[(t + 1) & 1][j] = Ab[(t + 1) * 512 + j * 64];
        }
        int kh = t / 3, kw = t % 3;
        int xc0 = (wc * 64 + l31 + 8 * kw - 8) & 127;   // circular column
        int xc1 = (xc0 + 32) & 127;
        int b0base = kh * ROWB + xc0 * 128 + lhi * 16, s0 = swz(xc0);
        int b1base = kh * ROWB + xc1 * 128 + lhi * 16, s1 = swz(xc1);
        #pragma unroll
        for (int ks = 0; ks < 4; ++ks) {   // K=16 per MFMA, 64 ic per tap
            bf16x8 a0 = aBuf[t & 1][ks];        // m=0 rows
            bf16x8 a1 = aBuf[t & 1][4 + ks];    // m=1 rows
            bf16x8 b0 = *reinterpret_cast<const bf16x8*>(xsB + ((b0base + ks * 32) ^ s0));
            bf16x8 b1 = *reinterpret_cast<const bf16x8*>(xsB + ((b1base + ks * 32) ^ s1));
            acc[0][0] = __builtin_amdgcn_mfma_f32_32x32x16_bf16(a0, b0, acc[0][0], 0, 0, 0);
            acc[0][1] = __builtin_amdgcn_mfma_f32_32x32x16_bf16(a0, b1, acc[0][1], 0, 0, 0);
            acc[1][0] = __builtin_amdgcn_mfma_f32_32x32x16_bf16(a1, b0, acc[1][0], 0, 0, 0);
            acc[1][1] = __builtin_amdgcn_mfma_f32_32x32x16_bf16(a1, b1, acc[1][1], 0, 0, 0);
        }
    }

    // ---- epilogue: bias + store. D: col=l31(w), row=(reg&3)+8*(reg>>2)+4*lhi ----
    int outbase = (n * OUT_CH) * HW * HW + h * HW;
    #pragma unroll
    for (int mi = 0; mi < 2; ++mi) {
        #pragma unroll
        for (int ni = 0; ni < 2; ++ni) {
            int wcol = wc * 64 + ni * 32 + l31;
            #pragma unroll
            for (int reg = 0; reg < 16; ++reg) {
                int oc = wr * 64 + mi * 32 + (reg & 3) + 8 * (reg >> 2) + 4 * lhi;
                y[outbase + oc * HW * HW + wcol] = acc[mi][ni][reg] + bias[oc];
            }
        }
    }
}

extern "C" void kernel_launch(void* const* d_in, const int* in_sizes, int n_in,
                              void* d_out, int out_size, void* d_ws, size_t ws_size,
                              hipStream_t stream) {
    const float* x = (const float*)d_in[0];
    const float* W = (const float*)d_in[1];
    const float* b = (const float*)d_in[2];
    float* y = (float*)d_out;

    unsigned short* Wl = (unsigned short*)d_ws;   // 147456 B

    hipLaunchKernelGGL(wprep_kernel, dim3((OUT_CH * IN_CH * KTAPS + 255) / 256), dim3(256), 0, stream, W, Wl);
    hipLaunchKernelGGL(conv_kernel_f, dim3(16 * HW), dim3(256), 0, stream, x, Wl, b, y);
}